// Round 8
// baseline (825.838 us; speedup 1.0000x reference)
//
#include <hip/hip_runtime.h>
#include <float.h>

#define B_SZ   64
#define T_FR   20
#define K_SEL  5
#define C_CH   3
#define D_SKIM 245760
#define HW224  50176
#define F4_IMG 12544        // HW224/4
#define K1_BLOCKS 768
#define K1_TILES  10        // 768 blocks * 10 tiles * BK32 == 245760
#define BK        32
#define GP_PARTS  4
#define F4_PART   3136      // F4_IMG/4
#define REPS      20        // DIAGNOSTIC amplification (single dispatch > fills)

// compile-time float4 component pick (dp is an unrolled literal)
#define AC(v, dp) ((dp) == 0 ? (v).x : (dp) == 1 ? (v).y : (dp) == 2 ? (v).z : (v).w)

// ---------------------------------------------------------------------------
// Kernel 1: per-block partial of fea = A[64,245760] @ W[245760,64].
// R8 = R4's proven structure (2-buffer, global_load_lds 16B, vmcnt(0)-drain +
// syncthreads per tile, W in LDS) with ONE change: LDS 48->32KB and
// __launch_bounds__(256,4) -> 4 blocks/CU, 16 waves/CU (was 12). Theory:
// skim is latency-bound (R5/R6/R7 pipeline variants all <= noise), so more
// resident waves per SIMD is the lever.
// DIAGNOSTIC: whole body runs REPS=20x inside one dispatch (idempotent slab
// write) so this dispatch exceeds the harness poison-fills (~480us) and
// surfaces in the top-5 counter rows with real VALUBusy/Occupancy/VGPR.
// ---------------------------------------------------------------------------
__global__ __launch_bounds__(256, 4) void skim_gemm_x20(
    const float* __restrict__ A, const float* __restrict__ W,
    float* __restrict__ partial) {
  __shared__ float lds[8192];          // 2 bufs x (A 2048 dw | W 2048 dw)
  const int t    = threadIdx.x;
  const int lane = t & 63;
  const int wav  = t >> 6;             // 0..3
  const int kb   = lane >> 3;          // 0..7 (b-group)
  const int b0   = kb << 3;
  const int j0   = (lane & 7) << 3;

  // staging geometry (per wave: 2 A-DMA + 2 W-DMA, 1KB each)
  const int ga0    = 2 * wav;
  const int arow0  = 8 * ga0 + (lane >> 3);
  const int aslot0 = (lane & 7) ^ (ga0 & 7);
  const int arow1  = 8 * (ga0 + 1) + (lane >> 3);
  const int aslot1 = (lane & 7) ^ ((ga0 + 1) & 7);
  const int wrow0  = 4 * ga0 + (lane >> 4);
  const int wcol0  = (lane & 15) << 2;
  const int wrow1  = 4 * (ga0 + 1) + (lane >> 4);

  const long dbase = (long)blockIdx.x * (K1_TILES * BK);

#define STAGE(bufsel, tile_)                                                   \
  {                                                                            \
    const long d0_ = dbase + (long)(tile_) * BK;                               \
    float* Ab = lds + (bufsel) * 4096;                                         \
    float* Wb = Ab + 2048;                                                     \
    __builtin_amdgcn_global_load_lds(                                          \
        (const __attribute__((address_space(1))) void*)(A + (long)arow0 * D_SKIM + d0_ + aslot0 * 4), \
        (__attribute__((address_space(3))) void*)(Ab + ga0 * 256), 16, 0, 0);  \
    __builtin_amdgcn_global_load_lds(                                          \
        (const __attribute__((address_space(1))) void*)(A + (long)arow1 * D_SKIM + d0_ + aslot1 * 4), \
        (__attribute__((address_space(3))) void*)(Ab + (ga0 + 1) * 256), 16, 0, 0); \
    __builtin_amdgcn_global_load_lds(                                          \
        (const __attribute__((address_space(1))) void*)(W + (d0_ + wrow0) * 64 + wcol0), \
        (__attribute__((address_space(3))) void*)(Wb + ga0 * 256), 16, 0, 0);  \
    __builtin_amdgcn_global_load_lds(                                          \
        (const __attribute__((address_space(1))) void*)(W + (d0_ + wrow1) * 64 + wcol0), \
        (__attribute__((address_space(3))) void*)(Wb + (ga0 + 1) * 256), 16, 0, 0); \
  }

#pragma unroll 1
  for (int rep = 0; rep < REPS; ++rep) {
    float acc[8][8];
#pragma unroll
    for (int i = 0; i < 8; ++i)
#pragma unroll
      for (int j = 0; j < 8; ++j) acc[i][j] = 0.f;

    STAGE(0, 0)
    asm volatile("s_waitcnt vmcnt(0)" ::: "memory");
    __syncthreads();

    for (int tile = 0; tile < K1_TILES; ++tile) {
      if (tile + 1 < K1_TILES) STAGE((tile + 1) & 1, tile + 1)
      const float* Ab = lds + (tile & 1) * 4096;
      const float* Wb = Ab + 2048;
#pragma unroll
      for (int chunk = 0; chunk < 2; ++chunk) {
        const int dc = (wav << 3) + (chunk << 2);
        const int sw = dc ^ (kb << 2);
        const float4 a0 = *reinterpret_cast<const float4*>(&Ab[(b0 + 0) * 32 + sw]);
        const float4 a1 = *reinterpret_cast<const float4*>(&Ab[(b0 + 1) * 32 + sw]);
        const float4 a2 = *reinterpret_cast<const float4*>(&Ab[(b0 + 2) * 32 + sw]);
        const float4 a3 = *reinterpret_cast<const float4*>(&Ab[(b0 + 3) * 32 + sw]);
        const float4 a4 = *reinterpret_cast<const float4*>(&Ab[(b0 + 4) * 32 + sw]);
        const float4 a5 = *reinterpret_cast<const float4*>(&Ab[(b0 + 5) * 32 + sw]);
        const float4 a6 = *reinterpret_cast<const float4*>(&Ab[(b0 + 6) * 32 + sw]);
        const float4 a7 = *reinterpret_cast<const float4*>(&Ab[(b0 + 7) * 32 + sw]);
#pragma unroll
        for (int dp = 0; dp < 4; ++dp) {
          const float4 wlo = *reinterpret_cast<const float4*>(&Wb[(dc + dp) * 64 + j0]);
          const float4 whi = *reinterpret_cast<const float4*>(&Wb[(dc + dp) * 64 + j0 + 4]);
#define FMA_ROW(i, av)                             \
          acc[i][0] = fmaf(av, wlo.x, acc[i][0]);  \
          acc[i][1] = fmaf(av, wlo.y, acc[i][1]);  \
          acc[i][2] = fmaf(av, wlo.z, acc[i][2]);  \
          acc[i][3] = fmaf(av, wlo.w, acc[i][3]);  \
          acc[i][4] = fmaf(av, whi.x, acc[i][4]);  \
          acc[i][5] = fmaf(av, whi.y, acc[i][5]);  \
          acc[i][6] = fmaf(av, whi.z, acc[i][6]);  \
          acc[i][7] = fmaf(av, whi.w, acc[i][7]);
          FMA_ROW(0, AC(a0, dp)) FMA_ROW(1, AC(a1, dp))
          FMA_ROW(2, AC(a2, dp)) FMA_ROW(3, AC(a3, dp))
          FMA_ROW(4, AC(a4, dp)) FMA_ROW(5, AC(a5, dp))
          FMA_ROW(6, AC(a6, dp)) FMA_ROW(7, AC(a7, dp))
#undef FMA_ROW
        }
      }
      asm volatile("s_waitcnt vmcnt(0)" ::: "memory");
      __syncthreads();
    }

    // ---- 2-round cross-wave reduce reusing both LDS buffers ----
    float* reg = lds + ((wav & 1) ? 4096 : 0);
    if (wav < 2) {
#pragma unroll
      for (int i = 0; i < 8; ++i) {
        *reinterpret_cast<float4*>(&reg[(b0 + i) * 64 + j0])     =
            make_float4(acc[i][0], acc[i][1], acc[i][2], acc[i][3]);
        *reinterpret_cast<float4*>(&reg[(b0 + i) * 64 + j0 + 4]) =
            make_float4(acc[i][4], acc[i][5], acc[i][6], acc[i][7]);
      }
    }
    __syncthreads();
    if (wav >= 2) {
#pragma unroll
      for (int i = 0; i < 8; ++i) {
        float4 lo = *reinterpret_cast<const float4*>(&reg[(b0 + i) * 64 + j0]);
        float4 hi = *reinterpret_cast<const float4*>(&reg[(b0 + i) * 64 + j0 + 4]);
        lo.x += acc[i][0]; lo.y += acc[i][1]; lo.z += acc[i][2]; lo.w += acc[i][3];
        hi.x += acc[i][4]; hi.y += acc[i][5]; hi.z += acc[i][6]; hi.w += acc[i][7];
        *reinterpret_cast<float4*>(&reg[(b0 + i) * 64 + j0])     = lo;
        *reinterpret_cast<float4*>(&reg[(b0 + i) * 64 + j0 + 4]) = hi;
      }
    }
    __syncthreads();
    {
      const float4* r0 = reinterpret_cast<const float4*>(lds);
      const float4* r1 = reinterpret_cast<const float4*>(lds + 4096);
      float4* outp = reinterpret_cast<float4*>(partial + (long)blockIdx.x * 4096);
#pragma unroll
      for (int k = 0; k < 4; ++k) {
        const int e = t + k * 256;
        float4 v0 = r0[e], v1 = r1[e];
        outp[e] = make_float4(v0.x + v1.x, v0.y + v1.y, v0.z + v1.z, v0.w + v1.w);
      }
    }
    __syncthreads();   // LDS safe before next rep's STAGE
  }
#undef STAGE
}

// ---------------------------------------------------------------------------
// Kernel 2: reduce 768 partial slabs -> fea; relu(+b_skim); logits via W_pol;
// stable top-5 (strict >, lowest index on ties = jax.lax.top_k), sorted asc.
// ---------------------------------------------------------------------------
__global__ __launch_bounds__(256) void policy_topk(
    const float* __restrict__ partial, const float* __restrict__ b_skim,
    const float* __restrict__ W_pol, const float* __restrict__ b_pol,
    int* __restrict__ idx_out) {
  const int b    = blockIdx.x;
  const int t    = threadIdx.x;
  const int lane = t & 63;
  const int wav  = t >> 6;
  __shared__ float red[4][64];
  __shared__ float vsh[64];
  __shared__ float lgsh[20];

  const int P4 = K1_BLOCKS / 4;        // 192 slabs per wave
  const float* base = partial + (long)(wav * P4) * 4096 + b * 64 + lane;
  float s = 0.f;
#pragma unroll 16
  for (int p = 0; p < P4; ++p) s += base[(long)p * 4096];
  red[wav][lane] = s;
  __syncthreads();

  if (wav == 0) {
    float fea = ((red[0][lane] + red[1][lane]) + (red[2][lane] + red[3][lane]))
                + b_skim[lane];
    vsh[lane] = fmaxf(fea, 0.f);
  }
  __syncthreads();

  if (t < 20) {
    float lg = b_pol[t];
#pragma unroll 8
    for (int k = 0; k < 64; ++k) lg = fmaf(vsh[k], W_pol[k * 20 + t], lg);
    lgsh[t] = lg;
  }
  __syncthreads();

  if (t == 0) {
    float lg[20];
#pragma unroll
    for (int i = 0; i < 20; ++i) lg[i] = lgsh[i];
    int sel[K_SEL];
#pragma unroll
    for (int s5 = 0; s5 < K_SEL; ++s5) {
      int bi = 0; float bv = lg[0];
      for (int i = 1; i < 20; ++i)
        if (lg[i] > bv) { bv = lg[i]; bi = i; }
      sel[s5] = bi; lg[bi] = -FLT_MAX;
    }
#pragma unroll
    for (int a = 1; a < K_SEL; ++a) {
      int v = sel[a], c = a;
      while (c > 0 && sel[c - 1] > v) { sel[c] = sel[c - 1]; --c; }
      sel[c] = v;
    }
#pragma unroll
    for (int s5 = 0; s5 < K_SEL; ++s5) idx_out[b * K_SEL + s5] = sel[s5];
  }
}

// ---------------------------------------------------------------------------
// Kernel 3: partial spatial sums of the 5 selected frames.
// 4 parts per (b,s,c) image -> 3840 blocks == 15 blocks/CU (no tail).
// ---------------------------------------------------------------------------
__global__ __launch_bounds__(256) void gather_pool(
    const float* __restrict__ F224, const int* __restrict__ idx,
    float* __restrict__ pooled_part) {
  const int blk  = blockIdx.x;
  const int part = blk & 3;
  const int img  = blk >> 2;           // b*15 + s*3 + c
  const int b = img / 15;
  const int r = img % 15;
  const int s = r / 3;
  const int c = r % 3;
  const int fr = idx[b * K_SEL + s];
  const float4* p4 = reinterpret_cast<const float4*>(F224) +
      ((long)(b * T_FR + fr) * C_CH + c) * F4_IMG + part * F4_PART;
  float sum = 0.f;
#pragma unroll 4
  for (int i = threadIdx.x; i < F4_PART; i += 256) {
    float4 v = p4[i];
    sum += (v.x + v.y) + (v.z + v.w);
  }
#pragma unroll
  for (int off = 32; off; off >>= 1) sum += __shfl_down(sum, off);
  __shared__ float red[4];
  if ((threadIdx.x & 63) == 0) red[threadIdx.x >> 6] = sum;
  __syncthreads();
  if (threadIdx.x == 0) pooled_part[blk] = (red[0] + red[1]) + (red[2] + red[3]);
}

// ---------------------------------------------------------------------------
// Kernel 4: out[b][n] = b_eval[n] + sum_k pooled[b][k] * W_eval[k][n]
// ---------------------------------------------------------------------------
__global__ __launch_bounds__(512) void eval_gemm(
    const float* __restrict__ pooled_part, const float* __restrict__ W_eval,
    const float* __restrict__ b_eval, float* __restrict__ out) {
  const int b = blockIdx.x;
  const int t = threadIdx.x;
  __shared__ float sh[60];
  __shared__ float pk[15];
  if (t < 60) sh[t] = pooled_part[b * 60 + t];
  __syncthreads();
  if (t < 15)
    pk[t] = ((sh[t * 4] + sh[t * 4 + 1]) + (sh[t * 4 + 2] + sh[t * 4 + 3]))
            * (1.0f / HW224);
  __syncthreads();
  if (t < 400) {
    float o = b_eval[t];
#pragma unroll
    for (int k = 0; k < 15; ++k) o = fmaf(pk[k], W_eval[k * 400 + t], o);
    out[b * 400 + t] = o;
  }
}

// ---------------------------------------------------------------------------
extern "C" void kernel_launch(void* const* d_in, const int* in_sizes, int n_in,
                              void* d_out, int out_size, void* d_ws, size_t ws_size,
                              hipStream_t stream) {
  const float* F64    = (const float*)d_in[0];
  const float* F224   = (const float*)d_in[1];
  const float* W_skim = (const float*)d_in[2];
  const float* b_skim = (const float*)d_in[3];
  const float* W_pol  = (const float*)d_in[4];
  const float* b_pol  = (const float*)d_in[5];
  const float* W_eval = (const float*)d_in[6];
  const float* b_eval = (const float*)d_in[7];
  float* out = (float*)d_out;

  char* ws = (char*)d_ws;
  float* partial     = (float*)ws;                         // 768*4096 floats
  int*   idx         = (int*)(ws + (size_t)K1_BLOCKS * 4096 * 4);
  float* pooled_part = (float*)(ws + (size_t)K1_BLOCKS * 4096 * 4 + 1280);

  skim_gemm_x20<<<K1_BLOCKS, 256, 0, stream>>>(F64, W_skim, partial);
  policy_topk<<<B_SZ, 256, 0, stream>>>(partial, b_skim, W_pol, b_pol, idx);
  gather_pool<<<B_SZ * K_SEL * C_CH * GP_PARTS, 256, 0, stream>>>(F224, idx, pooled_part);
  eval_gemm  <<<B_SZ, 512, 0, stream>>>(pooled_part, W_eval, b_eval, out);
}

// Round 9
// 257.523 us; speedup vs baseline: 3.2068x; 3.2068x over previous
//
#include <hip/hip_runtime.h>
#include <float.h>

#define B_SZ   64
#define T_FR   20
#define K_SEL  5
#define C_CH   3
#define D_SKIM 245760
#define HW224  50176
#define F4_IMG 12544        // HW224/4
#define K1_BLOCKS 768
#define KB_BLK    320       // K elements per block (768*320 == 245760)
#define NG        80        // groups of 4 k per block
#define GP_PARTS  4
#define F4_PART   3136      // F4_IMG/4

// compile-time float4 component pick (kk is an unrolled literal)
#define AC(v, kk) ((kk) == 0 ? (v).x : (kk) == 1 ? (v).y : (kk) == 2 ? (v).z : (v).w)

// ---------------------------------------------------------------------------
// Kernel 1 (R9 redesign): per-block partial of fea = A[64,245760]@W[245760,64]
// ZERO LDS / ZERO barriers. Decomposition exploits N=64 == wavefront:
//   - lane j owns output column j: W[k][lane] is a perfectly coalesced
//     per-lane global dword load (k-rows of W are 256B contiguous).
//   - A[r][k] is wave-uniform: row base hoisted to SGPR via readfirstlane,
//     so A loads are scalar/broadcast (1 request) and feed v_fmac as the
//     single allowed SGPR operand.
// 768 blocks x 512 threads (8 waves x 8 rows = full 64x64 tile per block,
// K-slice of 320 per block). Register ping-pong (explicit even/odd bodies,
// no dynamic reg indexing) prefetches group g+1 during group g's 64 FMA cyc.
// R8 counters motivating this: VGPR=64 (compiler killed ILP for occupancy),
// VALUBusy 37%, LDS pipe ~19us/CU intrinsically bound by 8-way-broadcast
// ds_reads. This removes the LDS pipe from the kernel entirely.
// ---------------------------------------------------------------------------
__global__ __launch_bounds__(512, 4) void skim_gemm(
    const float* __restrict__ A, const float* __restrict__ W,
    float* __restrict__ partial) {
  const int t    = threadIdx.x;
  const int lane = t & 63;
  const int wvu  = __builtin_amdgcn_readfirstlane(t >> 6);   // wave id 0..7
  const long k0  = (long)blockIdx.x * KB_BLK;

  const float* Ar[8];
#pragma unroll
  for (int r = 0; r < 8; ++r)
    Ar[r] = A + (long)(wvu * 8 + r) * D_SKIM + k0;
  const float* Wp = W + k0 * 64 + lane;

  float acc[8] = {0.f, 0.f, 0.f, 0.f, 0.f, 0.f, 0.f, 0.f};
  float4 aA[8], aB[8];
  float  wA[4], wB[4];

#define LDA(buf, g)                                                        \
  _Pragma("unroll") for (int r = 0; r < 8; ++r)                            \
      buf[r] = *reinterpret_cast<const float4*>(Ar[r] + (g) * 4);
#define LDW(buf, g)                                                        \
  _Pragma("unroll") for (int kk = 0; kk < 4; ++kk)                         \
      buf[kk] = Wp[((g) * 4 + kk) * 64];
#define FMA4(abuf, wbuf)                                                   \
  _Pragma("unroll") for (int kk = 0; kk < 4; ++kk) {                       \
    const float wv_ = wbuf[kk];                                            \
    _Pragma("unroll") for (int r = 0; r < 8; ++r)                          \
        acc[r] = fmaf(AC(abuf[r], kk), wv_, acc[r]);                       \
  }

  LDA(aA, 0)
  LDW(wA, 0)
#pragma unroll 1
  for (int g = 0; g < NG; g += 2) {
    LDA(aB, g + 1)                       // prefetch odd group
    LDW(wB, g + 1)
    FMA4(aA, wA)                         // compute even group
    if (g + 2 < NG) {
      LDA(aA, g + 2)                     // prefetch next even group
      LDW(wA, g + 2)
    }
    FMA4(aB, wB)                         // compute odd group
  }
#undef LDA
#undef LDW
#undef FMA4

  float* outp = partial + (long)blockIdx.x * 4096 + (wvu * 8) * 64 + lane;
#pragma unroll
  for (int r = 0; r < 8; ++r) outp[r * 64] = acc[r];
}

// ---------------------------------------------------------------------------
// Kernel 2: reduce 768 partial slabs -> fea; relu(+b_skim); logits via W_pol;
// stable top-5 (strict >, lowest index on ties = jax.lax.top_k), sorted asc.
// ---------------------------------------------------------------------------
__global__ __launch_bounds__(256) void policy_topk(
    const float* __restrict__ partial, const float* __restrict__ b_skim,
    const float* __restrict__ W_pol, const float* __restrict__ b_pol,
    int* __restrict__ idx_out) {
  const int b    = blockIdx.x;
  const int t    = threadIdx.x;
  const int lane = t & 63;
  const int wav  = t >> 6;
  __shared__ float red[4][64];
  __shared__ float vsh[64];
  __shared__ float lgsh[20];

  const int P4 = K1_BLOCKS / 4;        // 192 slabs per wave
  const float* base = partial + (long)(wav * P4) * 4096 + b * 64 + lane;
  float s = 0.f;
#pragma unroll 16
  for (int p = 0; p < P4; ++p) s += base[(long)p * 4096];
  red[wav][lane] = s;
  __syncthreads();

  if (wav == 0) {
    float fea = ((red[0][lane] + red[1][lane]) + (red[2][lane] + red[3][lane]))
                + b_skim[lane];
    vsh[lane] = fmaxf(fea, 0.f);
  }
  __syncthreads();

  if (t < 20) {
    float lg = b_pol[t];
#pragma unroll 8
    for (int k = 0; k < 64; ++k) lg = fmaf(vsh[k], W_pol[k * 20 + t], lg);
    lgsh[t] = lg;
  }
  __syncthreads();

  if (t == 0) {
    float lg[20];
#pragma unroll
    for (int i = 0; i < 20; ++i) lg[i] = lgsh[i];
    int sel[K_SEL];
#pragma unroll
    for (int s5 = 0; s5 < K_SEL; ++s5) {
      int bi = 0; float bv = lg[0];
      for (int i = 1; i < 20; ++i)
        if (lg[i] > bv) { bv = lg[i]; bi = i; }
      sel[s5] = bi; lg[bi] = -FLT_MAX;
    }
#pragma unroll
    for (int a = 1; a < K_SEL; ++a) {
      int v = sel[a], c = a;
      while (c > 0 && sel[c - 1] > v) { sel[c] = sel[c - 1]; --c; }
      sel[c] = v;
    }
#pragma unroll
    for (int s5 = 0; s5 < K_SEL; ++s5) idx_out[b * K_SEL + s5] = sel[s5];
  }
}

// ---------------------------------------------------------------------------
// Kernel 3: partial spatial sums of the 5 selected frames.
// 4 parts per (b,s,c) image -> 3840 blocks == 15 blocks/CU (no tail).
// ---------------------------------------------------------------------------
__global__ __launch_bounds__(256) void gather_pool(
    const float* __restrict__ F224, const int* __restrict__ idx,
    float* __restrict__ pooled_part) {
  const int blk  = blockIdx.x;
  const int part = blk & 3;
  const int img  = blk >> 2;           // b*15 + s*3 + c
  const int b = img / 15;
  const int r = img % 15;
  const int s = r / 3;
  const int c = r % 3;
  const int fr = idx[b * K_SEL + s];
  const float4* p4 = reinterpret_cast<const float4*>(F224) +
      ((long)(b * T_FR + fr) * C_CH + c) * F4_IMG + part * F4_PART;
  float sum = 0.f;
#pragma unroll 4
  for (int i = threadIdx.x; i < F4_PART; i += 256) {
    float4 v = p4[i];
    sum += (v.x + v.y) + (v.z + v.w);
  }
#pragma unroll
  for (int off = 32; off; off >>= 1) sum += __shfl_down(sum, off);
  __shared__ float red[4];
  if ((threadIdx.x & 63) == 0) red[threadIdx.x >> 6] = sum;
  __syncthreads();
  if (threadIdx.x == 0) pooled_part[blk] = (red[0] + red[1]) + (red[2] + red[3]);
}

// ---------------------------------------------------------------------------
// Kernel 4: out[b][n] = b_eval[n] + sum_k pooled[b][k] * W_eval[k][n]
// ---------------------------------------------------------------------------
__global__ __launch_bounds__(512) void eval_gemm(
    const float* __restrict__ pooled_part, const float* __restrict__ W_eval,
    const float* __restrict__ b_eval, float* __restrict__ out) {
  const int b = blockIdx.x;
  const int t = threadIdx.x;
  __shared__ float sh[60];
  __shared__ float pk[15];
  if (t < 60) sh[t] = pooled_part[b * 60 + t];
  __syncthreads();
  if (t < 15)
    pk[t] = ((sh[t * 4] + sh[t * 4 + 1]) + (sh[t * 4 + 2] + sh[t * 4 + 3]))
            * (1.0f / HW224);
  __syncthreads();
  if (t < 400) {
    float o = b_eval[t];
#pragma unroll
    for (int k = 0; k < 15; ++k) o = fmaf(pk[k], W_eval[k * 400 + t], o);
    out[b * 400 + t] = o;
  }
}

// ---------------------------------------------------------------------------
extern "C" void kernel_launch(void* const* d_in, const int* in_sizes, int n_in,
                              void* d_out, int out_size, void* d_ws, size_t ws_size,
                              hipStream_t stream) {
  const float* F64    = (const float*)d_in[0];
  const float* F224   = (const float*)d_in[1];
  const float* W_skim = (const float*)d_in[2];
  const float* b_skim = (const float*)d_in[3];
  const float* W_pol  = (const float*)d_in[4];
  const float* b_pol  = (const float*)d_in[5];
  const float* W_eval = (const float*)d_in[6];
  const float* b_eval = (const float*)d_in[7];
  float* out = (float*)d_out;

  char* ws = (char*)d_ws;
  float* partial     = (float*)ws;                         // 768*4096 floats
  int*   idx         = (int*)(ws + (size_t)K1_BLOCKS * 4096 * 4);
  float* pooled_part = (float*)(ws + (size_t)K1_BLOCKS * 4096 * 4 + 1280);

  skim_gemm  <<<K1_BLOCKS, 512, 0, stream>>>(F64, W_skim, partial);
  policy_topk<<<B_SZ, 256, 0, stream>>>(partial, b_skim, W_pol, b_pol, idx);
  gather_pool<<<B_SZ * K_SEL * C_CH * GP_PARTS, 256, 0, stream>>>(F224, idx, pooled_part);
  eval_gemm  <<<B_SZ, 512, 0, stream>>>(pooled_part, W_eval, b_eval, out);
}

// Round 11
// 90.381 us; speedup vs baseline: 9.1373x; 2.8493x over previous
//
#include <hip/hip_runtime.h>
#include <float.h>

#define B_SZ   64
#define T_FR   20
#define K_SEL  5
#define C_CH   3
#define D_SKIM 245760
#define HW224  50176
#define F4_IMG 12544        // HW224/4
#define K1_BLOCKS 768
#define K1_TILES  10        // 768 blocks * 10 tiles * BK32 == 245760
#define BK        32
#define GP_PARTS  4
#define F4_PART   3136      // F4_IMG/4

// compile-time float4 component pick (kk is an unrolled literal)
#define AC(v, kk) ((kk) == 0 ? (v).x : (kk) == 1 ? (v).y : (kk) == 2 ? (v).z : (v).w)

// ---------------------------------------------------------------------------
// Kernel 1: per-block partial of fea = A[64,245760] @ W[245760,64].
// R11 = R10 with the correctness bug fixed: source pre-swizzle (16B slot
// s^1 for s>=8) and XOR'd read address compose to IDENTITY on the data --
// w[2dp] is already the lower half and w[2dp+1] the upper half for ALL
// lanes. R10's extra "unswap" select double-corrected and swapped columns
// 32-63. (Rule 21: both-sides-or-neither, same involution -> no 3rd step.)
// Retained R10 perf changes vs R4:
//  (1) all 16 fragment ds_read_b128 hoisted to chunk top (one latency
//      bubble/chunk instead of per-dp; R8 showed latency-stall bound).
//  (2) W reads conflict-free: slots {0,2,4,6,9,11,13,15} cover all 32 banks.
// ---------------------------------------------------------------------------
__global__ __launch_bounds__(256) void skim_gemm(
    const float* __restrict__ A, const float* __restrict__ W,
    float* __restrict__ partial) {
  __shared__ float lds[8192];          // 2 bufs x (A 2048 dw | W 2048 dw)
  const int t    = threadIdx.x;
  const int lane = t & 63;
  const int wav  = t >> 6;             // 0..3
  const int kb   = lane >> 3;          // 0..7 (b-group)
  const int b0   = kb << 3;
  const int jo   = lane & 7;
  const int j0   = jo << 3;
  const int jsw  = jo & 4;             // W read-side swizzle (dword XOR)

  // staging geometry (per wave: 2 A-DMA + 2 W-DMA, 1KB each)
  const int ga0    = 2 * wav;
  const int arow0  = 8 * ga0 + kb;
  const int aslot0 = (lane & 7) ^ (ga0 & 7);
  const int arow1  = 8 * (ga0 + 1) + kb;
  const int aslot1 = (lane & 7) ^ ((ga0 + 1) & 7);
  const int wrow0  = 4 * ga0 + (lane >> 4);
  const int wrow1  = 4 * (ga0 + 1) + (lane >> 4);
  // W source pre-swizzle: LDS 16B slot s receives global slot s^1 for s>=8
  const int wsl    = (lane & 15);
  const int wcol0  = (wsl << 2) ^ (((wsl >> 3) & 1) << 2);

  float acc[8][8];
#pragma unroll
  for (int i = 0; i < 8; ++i)
#pragma unroll
    for (int j = 0; j < 8; ++j) acc[i][j] = 0.f;

  const long dbase = (long)blockIdx.x * (K1_TILES * BK);

#define STAGE(bufsel, tile_)                                                   \
  {                                                                            \
    const long d0_ = dbase + (long)(tile_) * BK;                               \
    float* Ab = lds + (bufsel) * 4096;                                         \
    float* Wb = Ab + 2048;                                                     \
    __builtin_amdgcn_global_load_lds(                                          \
        (const __attribute__((address_space(1))) void*)(A + (long)arow0 * D_SKIM + d0_ + aslot0 * 4), \
        (__attribute__((address_space(3))) void*)(Ab + ga0 * 256), 16, 0, 0);  \
    __builtin_amdgcn_global_load_lds(                                          \
        (const __attribute__((address_space(1))) void*)(A + (long)arow1 * D_SKIM + d0_ + aslot1 * 4), \
        (__attribute__((address_space(3))) void*)(Ab + (ga0 + 1) * 256), 16, 0, 0); \
    __builtin_amdgcn_global_load_lds(                                          \
        (const __attribute__((address_space(1))) void*)(W + (d0_ + wrow0) * 64 + wcol0), \
        (__attribute__((address_space(3))) void*)(Wb + ga0 * 256), 16, 0, 0);  \
    __builtin_amdgcn_global_load_lds(                                          \
        (const __attribute__((address_space(1))) void*)(W + (d0_ + wrow1) * 64 + wcol0), \
        (__attribute__((address_space(3))) void*)(Wb + (ga0 + 1) * 256), 16, 0, 0); \
  }

  STAGE(0, 0)
  asm volatile("s_waitcnt vmcnt(0)" ::: "memory");
  __syncthreads();

  for (int tile = 0; tile < K1_TILES; ++tile) {
    if (tile + 1 < K1_TILES) STAGE((tile + 1) & 1, tile + 1)
    const float* Ab = lds + (tile & 1) * 4096;
    const float* Wb = Ab + 2048;
#pragma unroll
    for (int chunk = 0; chunk < 2; ++chunk) {
      const int dc = (wav << 3) + (chunk << 2);
      const int sw = dc ^ (kb << 2);
      // ---- hoisted fragment loads: 16 ds_read_b128, no FMA interleave ----
      // wlo[dp]=w[2dp], whi[dp]=w[2dp+1] directly: XOR'd read addr + XOR'd
      // source contents compose to identity (NO further unswap -- R10 bug).
      float4 a[8], wlo[4], whi[4];
#pragma unroll
      for (int i = 0; i < 8; ++i)
        a[i] = *reinterpret_cast<const float4*>(&Ab[(b0 + i) * 32 + sw]);
#pragma unroll
      for (int dp = 0; dp < 4; ++dp) {
        wlo[dp] = *reinterpret_cast<const float4*>(&Wb[(dc + dp) * 64 + (j0 ^ jsw)]);
        whi[dp] = *reinterpret_cast<const float4*>(&Wb[(dc + dp) * 64 + ((j0 + 4) ^ jsw)]);
      }
#pragma unroll
      for (int dp = 0; dp < 4; ++dp) {
#define FMA_ROW(i, av)                                     \
        acc[i][0] = fmaf(av, wlo[dp].x, acc[i][0]);        \
        acc[i][1] = fmaf(av, wlo[dp].y, acc[i][1]);        \
        acc[i][2] = fmaf(av, wlo[dp].z, acc[i][2]);        \
        acc[i][3] = fmaf(av, wlo[dp].w, acc[i][3]);        \
        acc[i][4] = fmaf(av, whi[dp].x, acc[i][4]);        \
        acc[i][5] = fmaf(av, whi[dp].y, acc[i][5]);        \
        acc[i][6] = fmaf(av, whi[dp].z, acc[i][6]);        \
        acc[i][7] = fmaf(av, whi[dp].w, acc[i][7]);
        FMA_ROW(0, AC(a[0], dp)) FMA_ROW(1, AC(a[1], dp))
        FMA_ROW(2, AC(a[2], dp)) FMA_ROW(3, AC(a[3], dp))
        FMA_ROW(4, AC(a[4], dp)) FMA_ROW(5, AC(a[5], dp))
        FMA_ROW(6, AC(a[6], dp)) FMA_ROW(7, AC(a[7], dp))
#undef FMA_ROW
      }
    }
    asm volatile("s_waitcnt vmcnt(0)" ::: "memory");
    __syncthreads();
  }
#undef STAGE

  // ---- 2-round cross-wave reduce reusing both LDS buffers ----
  float* reg = lds + ((wav & 1) ? 4096 : 0);
  if (wav < 2) {
#pragma unroll
    for (int i = 0; i < 8; ++i) {
      *reinterpret_cast<float4*>(&reg[(b0 + i) * 64 + j0])     =
          make_float4(acc[i][0], acc[i][1], acc[i][2], acc[i][3]);
      *reinterpret_cast<float4*>(&reg[(b0 + i) * 64 + j0 + 4]) =
          make_float4(acc[i][4], acc[i][5], acc[i][6], acc[i][7]);
    }
  }
  __syncthreads();
  if (wav >= 2) {
#pragma unroll
    for (int i = 0; i < 8; ++i) {
      float4 lo = *reinterpret_cast<const float4*>(&reg[(b0 + i) * 64 + j0]);
      float4 hi = *reinterpret_cast<const float4*>(&reg[(b0 + i) * 64 + j0 + 4]);
      lo.x += acc[i][0]; lo.y += acc[i][1]; lo.z += acc[i][2]; lo.w += acc[i][3];
      hi.x += acc[i][4]; hi.y += acc[i][5]; hi.z += acc[i][6]; hi.w += acc[i][7];
      *reinterpret_cast<float4*>(&reg[(b0 + i) * 64 + j0])     = lo;
      *reinterpret_cast<float4*>(&reg[(b0 + i) * 64 + j0 + 4]) = hi;
    }
  }
  __syncthreads();
  const float4* r0 = reinterpret_cast<const float4*>(lds);
  const float4* r1 = reinterpret_cast<const float4*>(lds + 4096);
  float4* outp = reinterpret_cast<float4*>(partial + (long)blockIdx.x * 4096);
#pragma unroll
  for (int k = 0; k < 4; ++k) {
    const int e = t + k * 256;
    float4 v0 = r0[e], v1 = r1[e];
    outp[e] = make_float4(v0.x + v1.x, v0.y + v1.y, v0.z + v1.z, v0.w + v1.w);
  }
}

// ---------------------------------------------------------------------------
// Kernel 2: reduce 768 partial slabs -> fea; relu(+b_skim); logits via W_pol;
// stable top-5 (strict >, lowest index on ties = jax.lax.top_k), sorted asc.
// ---------------------------------------------------------------------------
__global__ __launch_bounds__(256) void policy_topk(
    const float* __restrict__ partial, const float* __restrict__ b_skim,
    const float* __restrict__ W_pol, const float* __restrict__ b_pol,
    int* __restrict__ idx_out) {
  const int b    = blockIdx.x;
  const int t    = threadIdx.x;
  const int lane = t & 63;
  const int wav  = t >> 6;
  __shared__ float red[4][64];
  __shared__ float vsh[64];
  __shared__ float lgsh[20];

  const int P4 = K1_BLOCKS / 4;        // 192 slabs per wave
  const float* base = partial + (long)(wav * P4) * 4096 + b * 64 + lane;
  float s = 0.f;
#pragma unroll 16
  for (int p = 0; p < P4; ++p) s += base[(long)p * 4096];
  red[wav][lane] = s;
  __syncthreads();

  if (wav == 0) {
    float fea = ((red[0][lane] + red[1][lane]) + (red[2][lane] + red[3][lane]))
                + b_skim[lane];
    vsh[lane] = fmaxf(fea, 0.f);
  }
  __syncthreads();

  if (t < 20) {
    float lg = b_pol[t];
#pragma unroll 8
    for (int k = 0; k < 64; ++k) lg = fmaf(vsh[k], W_pol[k * 20 + t], lg);
    lgsh[t] = lg;
  }
  __syncthreads();

  if (t == 0) {
    float lg[20];
#pragma unroll
    for (int i = 0; i < 20; ++i) lg[i] = lgsh[i];
    int sel[K_SEL];
#pragma unroll
    for (int s5 = 0; s5 < K_SEL; ++s5) {
      int bi = 0; float bv = lg[0];
      for (int i = 1; i < 20; ++i)
        if (lg[i] > bv) { bv = lg[i]; bi = i; }
      sel[s5] = bi; lg[bi] = -FLT_MAX;
    }
#pragma unroll
    for (int a = 1; a < K_SEL; ++a) {
      int v = sel[a], c = a;
      while (c > 0 && sel[c - 1] > v) { sel[c] = sel[c - 1]; --c; }
      sel[c] = v;
    }
#pragma unroll
    for (int s5 = 0; s5 < K_SEL; ++s5) idx_out[b * K_SEL + s5] = sel[s5];
  }
}

// ---------------------------------------------------------------------------
// Kernel 3: partial spatial sums of the 5 selected frames.
// 4 parts per (b,s,c) image -> 3840 blocks == 15 blocks/CU (no tail).
// ---------------------------------------------------------------------------
__global__ __launch_bounds__(256) void gather_pool(
    const float* __restrict__ F224, const int* __restrict__ idx,
    float* __restrict__ pooled_part) {
  const int blk  = blockIdx.x;
  const int part = blk & 3;
  const int img  = blk >> 2;           // b*15 + s*3 + c
  const int b = img / 15;
  const int r = img % 15;
  const int s = r / 3;
  const int c = r % 3;
  const int fr = idx[b * K_SEL + s];
  const float4* p4 = reinterpret_cast<const float4*>(F224) +
      ((long)(b * T_FR + fr) * C_CH + c) * F4_IMG + part * F4_PART;
  float sum = 0.f;
#pragma unroll 4
  for (int i = threadIdx.x; i < F4_PART; i += 256) {
    float4 v = p4[i];
    sum += (v.x + v.y) + (v.z + v.w);
  }
#pragma unroll
  for (int off = 32; off; off >>= 1) sum += __shfl_down(sum, off);
  __shared__ float red[4];
  if ((threadIdx.x & 63) == 0) red[threadIdx.x >> 6] = sum;
  __syncthreads();
  if (threadIdx.x == 0) pooled_part[blk] = (red[0] + red[1]) + (red[2] + red[3]);
}

// ---------------------------------------------------------------------------
// Kernel 4: out[b][n] = b_eval[n] + sum_k pooled[b][k] * W_eval[k][n]
// ---------------------------------------------------------------------------
__global__ __launch_bounds__(512) void eval_gemm(
    const float* __restrict__ pooled_part, const float* __restrict__ W_eval,
    const float* __restrict__ b_eval, float* __restrict__ out) {
  const int b = blockIdx.x;
  const int t = threadIdx.x;
  __shared__ float sh[60];
  __shared__ float pk[15];
  if (t < 60) sh[t] = pooled_part[b * 60 + t];
  __syncthreads();
  if (t < 15)
    pk[t] = ((sh[t * 4] + sh[t * 4 + 1]) + (sh[t * 4 + 2] + sh[t * 4 + 3]))
            * (1.0f / HW224);
  __syncthreads();
  if (t < 400) {
    float o = b_eval[t];
#pragma unroll
    for (int k = 0; k < 15; ++k) o = fmaf(pk[k], W_eval[k * 400 + t], o);
    out[b * 400 + t] = o;
  }
}

// ---------------------------------------------------------------------------
extern "C" void kernel_launch(void* const* d_in, const int* in_sizes, int n_in,
                              void* d_out, int out_size, void* d_ws, size_t ws_size,
                              hipStream_t stream) {
  const float* F64    = (const float*)d_in[0];
  const float* F224   = (const float*)d_in[1];
  const float* W_skim = (const float*)d_in[2];
  const float* b_skim = (const float*)d_in[3];
  const float* W_pol  = (const float*)d_in[4];
  const float* b_pol  = (const float*)d_in[5];
  const float* W_eval = (const float*)d_in[6];
  const float* b_eval = (const float*)d_in[7];
  float* out = (float*)d_out;

  char* ws = (char*)d_ws;
  float* partial     = (float*)ws;                         // 768*4096 floats
  int*   idx         = (int*)(ws + (size_t)K1_BLOCKS * 4096 * 4);
  float* pooled_part = (float*)(ws + (size_t)K1_BLOCKS * 4096 * 4 + 1280);

  skim_gemm  <<<K1_BLOCKS, 256, 0, stream>>>(F64, W_skim, partial);
  policy_topk<<<B_SZ, 256, 0, stream>>>(partial, b_skim, W_pol, b_pol, idx);
  gather_pool<<<B_SZ * K_SEL * C_CH * GP_PARTS, 256, 0, stream>>>(F224, idx, pooled_part);
  eval_gemm  <<<B_SZ, 512, 0, stream>>>(pooled_part, W_eval, b_eval, out);
}

// Round 12
// 85.986 us; speedup vs baseline: 9.6043x; 1.0511x over previous
//
#include <hip/hip_runtime.h>
#include <float.h>

#define B_SZ   64
#define T_FR   20
#define K_SEL  5
#define C_CH   3
#define D_SKIM 245760
#define HW224  50176
#define F4_IMG 12544        // HW224/4
#define K1_BLOCKS 768
#define K1_TILES  10        // 768 blocks * 10 tiles * BK32 == 245760
#define BK        32
#define GP_PARTS  4
#define F4_PART   3136      // F4_IMG/4

// compile-time float4 component pick (kk is an unrolled literal)
#define AC(v, kk) ((kk) == 0 ? (v).x : (kk) == 1 ? (v).y : (kk) == 2 ? (v).z : (v).w)

// ---------------------------------------------------------------------------
// Kernel 1 (R12): per-block partial of fea = A[64,245760] @ W[245760,64].
// BARRIER-FREE K-loop. R4..R11 all plateau at skim~40us (floor ~20us) because
// the per-tile all-wave barrier forces LDS-burst and FMA-burst phase alignment
// (R8: VALUBusy 37%, every pipe <50%). Fix: the block's work factors per wave
// -- wave w needs A[all rows][its 8 d] and W[its 8 d][all j] -- so each wave
// DMAs its OWN 4KB slice into its OWN private LDS ring (global_load_lds has
// per-lane SOURCE addresses), ring-3, depth-2 prefetch, per-wave vmcnt(4).
// No __syncthreads until the epilogue reduce. 12 independent wave-pipelines
// per CU decorrelate -> pipes overlap statistically.
// A-gather source lane permutation arow = l ^ ((l>>3)&7) (involution): the
// a-fragment read (rows b0..b0+7, fixed i, kb varies) hits slot quads i^kb
// -> all 8 bank-quads, conflict-free. Per-row 128B line = exactly one tile's
// d-range -> HBM traffic unchanged (A+W read once).
// FMA order per output identical to R4/R11 -> bit-identical result.
// ---------------------------------------------------------------------------
__global__ __launch_bounds__(256) void skim_gemm(
    const float* __restrict__ A, const float* __restrict__ W,
    float* __restrict__ partial) {
  __shared__ float lds[12288];   // 4 waves x ring-3 x 1024 floats (48 KB)
  const int t    = threadIdx.x;
  const int lane = t & 63;
  const int wav  = t >> 6;             // 0..3
  const int kb   = lane >> 3;          // 0..7 (b-group)
  const int b0   = kb << 3;
  const int jo   = lane & 7;
  const int j0   = jo << 3;

  // DMA geometry (all per-wave, 4 instrs/tile):
  const int arow = lane ^ ((lane >> 3) & 7);   // A source-lane involution
  const int wrow = lane >> 4;                  // 0..3 (W row within half)
  const int wcol = (lane & 15) << 2;           // 0..60
  float* mybuf = lds + wav * 3072;             // 3 bufs x 1024 floats

  float acc[8][8];
#pragma unroll
  for (int i = 0; i < 8; ++i)
#pragma unroll
    for (int j = 0; j < 8; ++j) acc[i][j] = 0.f;

  const long dbase = (long)blockIdx.x * (K1_TILES * BK);

  // buffer layout (1024 floats): A chunk0 [0,256) | A chunk1 [256,512) |
  //                              W rows 0-3 [512,768) | W rows 4-7 [768,1024)
#define STAGE(bufsel, tile_)                                                   \
  {                                                                            \
    const long d0_ = dbase + (long)(tile_) * BK + (wav << 3);                  \
    float* Ab = mybuf + (bufsel) * 1024;                                       \
    float* Wb = Ab + 512;                                                      \
    __builtin_amdgcn_global_load_lds(                                          \
        (const __attribute__((address_space(1))) void*)(A + (long)arow * D_SKIM + d0_), \
        (__attribute__((address_space(3))) void*)(Ab), 16, 0, 0);              \
    __builtin_amdgcn_global_load_lds(                                          \
        (const __attribute__((address_space(1))) void*)(A + (long)arow * D_SKIM + d0_ + 4), \
        (__attribute__((address_space(3))) void*)(Ab + 256), 16, 0, 0);        \
    __builtin_amdgcn_global_load_lds(                                          \
        (const __attribute__((address_space(1))) void*)(W + (d0_ + wrow) * 64 + wcol), \
        (__attribute__((address_space(3))) void*)(Wb), 16, 0, 0);              \
    __builtin_amdgcn_global_load_lds(                                          \
        (const __attribute__((address_space(1))) void*)(W + (d0_ + 4 + wrow) * 64 + wcol), \
        (__attribute__((address_space(3))) void*)(Wb + 256), 16, 0, 0);        \
  }

  STAGE(0, 0)
  STAGE(1, 1)

  for (int tile = 0; tile < K1_TILES; ++tile) {
    if (tile < K1_TILES - 1) {
      asm volatile("s_waitcnt vmcnt(4)" ::: "memory");  // this wave's tile t landed
    } else {
      asm volatile("s_waitcnt vmcnt(0)" ::: "memory");
    }
    __builtin_amdgcn_sched_barrier(0);
    const float* Ab = mybuf + (tile % 3) * 1024;
    const float* Wb = Ab + 512;
#pragma unroll
    for (int c = 0; c < 2; ++c) {
      // a[i] = 4 d-values of row b0+i, at involution slot (b0+i)^kb
      float4 a[8];
#pragma unroll
      for (int i = 0; i < 8; ++i)
        a[i] = *reinterpret_cast<const float4*>(&Ab[c * 256 + (((b0 + i) ^ kb) << 2)]);
#pragma unroll
      for (int dp = 0; dp < 4; ++dp) {
        const float4 wlo = *reinterpret_cast<const float4*>(&Wb[(c * 4 + dp) * 64 + j0]);
        const float4 whi = *reinterpret_cast<const float4*>(&Wb[(c * 4 + dp) * 64 + j0 + 4]);
#define FMA_ROW(i, av)                             \
        acc[i][0] = fmaf(av, wlo.x, acc[i][0]);    \
        acc[i][1] = fmaf(av, wlo.y, acc[i][1]);    \
        acc[i][2] = fmaf(av, wlo.z, acc[i][2]);    \
        acc[i][3] = fmaf(av, wlo.w, acc[i][3]);    \
        acc[i][4] = fmaf(av, whi.x, acc[i][4]);    \
        acc[i][5] = fmaf(av, whi.y, acc[i][5]);    \
        acc[i][6] = fmaf(av, whi.z, acc[i][6]);    \
        acc[i][7] = fmaf(av, whi.w, acc[i][7]);
        FMA_ROW(0, AC(a[0], dp)) FMA_ROW(1, AC(a[1], dp))
        FMA_ROW(2, AC(a[2], dp)) FMA_ROW(3, AC(a[3], dp))
        FMA_ROW(4, AC(a[4], dp)) FMA_ROW(5, AC(a[5], dp))
        FMA_ROW(6, AC(a[6], dp)) FMA_ROW(7, AC(a[7], dp))
#undef FMA_ROW
      }
    }
    __builtin_amdgcn_sched_barrier(0);
    if (tile + 2 < K1_TILES) STAGE((tile + 2) % 3, tile + 2)
  }
#undef STAGE

  // ---- epilogue: 2-round cross-wave reduce (identical to R4/R11) ----
  __syncthreads();
  float* reg = lds + ((wav & 1) ? 4096 : 0);
  if (wav < 2) {
#pragma unroll
    for (int i = 0; i < 8; ++i) {
      *reinterpret_cast<float4*>(&reg[(b0 + i) * 64 + j0])     =
          make_float4(acc[i][0], acc[i][1], acc[i][2], acc[i][3]);
      *reinterpret_cast<float4*>(&reg[(b0 + i) * 64 + j0 + 4]) =
          make_float4(acc[i][4], acc[i][5], acc[i][6], acc[i][7]);
    }
  }
  __syncthreads();
  if (wav >= 2) {
#pragma unroll
    for (int i = 0; i < 8; ++i) {
      float4 lo = *reinterpret_cast<const float4*>(&reg[(b0 + i) * 64 + j0]);
      float4 hi = *reinterpret_cast<const float4*>(&reg[(b0 + i) * 64 + j0 + 4]);
      lo.x += acc[i][0]; lo.y += acc[i][1]; lo.z += acc[i][2]; lo.w += acc[i][3];
      hi.x += acc[i][4]; hi.y += acc[i][5]; hi.z += acc[i][6]; hi.w += acc[i][7];
      *reinterpret_cast<float4*>(&reg[(b0 + i) * 64 + j0])     = lo;
      *reinterpret_cast<float4*>(&reg[(b0 + i) * 64 + j0 + 4]) = hi;
    }
  }
  __syncthreads();
  const float4* r0 = reinterpret_cast<const float4*>(lds);
  const float4* r1 = reinterpret_cast<const float4*>(lds + 4096);
  float4* outp = reinterpret_cast<float4*>(partial + (long)blockIdx.x * 4096);
#pragma unroll
  for (int k = 0; k < 4; ++k) {
    const int e = t + k * 256;
    float4 v0 = r0[e], v1 = r1[e];
    outp[e] = make_float4(v0.x + v1.x, v0.y + v1.y, v0.z + v1.z, v0.w + v1.w);
  }
}

// ---------------------------------------------------------------------------
// Kernel 2: reduce 768 partial slabs -> fea; relu(+b_skim); logits via W_pol;
// stable top-5 (strict >, lowest index on ties = jax.lax.top_k), sorted asc.
// ---------------------------------------------------------------------------
__global__ __launch_bounds__(256) void policy_topk(
    const float* __restrict__ partial, const float* __restrict__ b_skim,
    const float* __restrict__ W_pol, const float* __restrict__ b_pol,
    int* __restrict__ idx_out) {
  const int b    = blockIdx.x;
  const int t    = threadIdx.x;
  const int lane = t & 63;
  const int wav  = t >> 6;
  __shared__ float red[4][64];
  __shared__ float vsh[64];
  __shared__ float lgsh[20];

  const int P4 = K1_BLOCKS / 4;        // 192 slabs per wave
  const float* base = partial + (long)(wav * P4) * 4096 + b * 64 + lane;
  float s = 0.f;
#pragma unroll 16
  for (int p = 0; p < P4; ++p) s += base[(long)p * 4096];
  red[wav][lane] = s;
  __syncthreads();

  if (wav == 0) {
    float fea = ((red[0][lane] + red[1][lane]) + (red[2][lane] + red[3][lane]))
                + b_skim[lane];
    vsh[lane] = fmaxf(fea, 0.f);
  }
  __syncthreads();

  if (t < 20) {
    float lg = b_pol[t];
#pragma unroll 8
    for (int k = 0; k < 64; ++k) lg = fmaf(vsh[k], W_pol[k * 20 + t], lg);
    lgsh[t] = lg;
  }
  __syncthreads();

  if (t == 0) {
    float lg[20];
#pragma unroll
    for (int i = 0; i < 20; ++i) lg[i] = lgsh[i];
    int sel[K_SEL];
#pragma unroll
    for (int s5 = 0; s5 < K_SEL; ++s5) {
      int bi = 0; float bv = lg[0];
      for (int i = 1; i < 20; ++i)
        if (lg[i] > bv) { bv = lg[i]; bi = i; }
      sel[s5] = bi; lg[bi] = -FLT_MAX;
    }
#pragma unroll
    for (int a = 1; a < K_SEL; ++a) {
      int v = sel[a], c = a;
      while (c > 0 && sel[c - 1] > v) { sel[c] = sel[c - 1]; --c; }
      sel[c] = v;
    }
#pragma unroll
    for (int s5 = 0; s5 < K_SEL; ++s5) idx_out[b * K_SEL + s5] = sel[s5];
  }
}

// ---------------------------------------------------------------------------
// Kernel 3: partial spatial sums of the 5 selected frames.
// 4 parts per (b,s,c) image -> 3840 blocks == 15 blocks/CU (no tail).
// ---------------------------------------------------------------------------
__global__ __launch_bounds__(256) void gather_pool(
    const float* __restrict__ F224, const int* __restrict__ idx,
    float* __restrict__ pooled_part) {
  const int blk  = blockIdx.x;
  const int part = blk & 3;
  const int img  = blk >> 2;           // b*15 + s*3 + c
  const int b = img / 15;
  const int r = img % 15;
  const int s = r / 3;
  const int c = r % 3;
  const int fr = idx[b * K_SEL + s];
  const float4* p4 = reinterpret_cast<const float4*>(F224) +
      ((long)(b * T_FR + fr) * C_CH + c) * F4_IMG + part * F4_PART;
  float sum = 0.f;
#pragma unroll 4
  for (int i = threadIdx.x; i < F4_PART; i += 256) {
    float4 v = p4[i];
    sum += (v.x + v.y) + (v.z + v.w);
  }
#pragma unroll
  for (int off = 32; off; off >>= 1) sum += __shfl_down(sum, off);
  __shared__ float red[4];
  if ((threadIdx.x & 63) == 0) red[threadIdx.x >> 6] = sum;
  __syncthreads();
  if (threadIdx.x == 0) pooled_part[blk] = (red[0] + red[1]) + (red[2] + red[3]);
}

// ---------------------------------------------------------------------------
// Kernel 4: out[b][n] = b_eval[n] + sum_k pooled[b][k] * W_eval[k][n]
// ---------------------------------------------------------------------------
__global__ __launch_bounds__(512) void eval_gemm(
    const float* __restrict__ pooled_part, const float* __restrict__ W_eval,
    const float* __restrict__ b_eval, float* __restrict__ out) {
  const int b = blockIdx.x;
  const int t = threadIdx.x;
  __shared__ float sh[60];
  __shared__ float pk[15];
  if (t < 60) sh[t] = pooled_part[b * 60 + t];
  __syncthreads();
  if (t < 15)
    pk[t] = ((sh[t * 4] + sh[t * 4 + 1]) + (sh[t * 4 + 2] + sh[t * 4 + 3]))
            * (1.0f / HW224);
  __syncthreads();
  if (t < 400) {
    float o = b_eval[t];
#pragma unroll
    for (int k = 0; k < 15; ++k) o = fmaf(pk[k], W_eval[k * 400 + t], o);
    out[b * 400 + t] = o;
  }
}

// ---------------------------------------------------------------------------
extern "C" void kernel_launch(void* const* d_in, const int* in_sizes, int n_in,
                              void* d_out, int out_size, void* d_ws, size_t ws_size,
                              hipStream_t stream) {
  const float* F64    = (const float*)d_in[0];
  const float* F224   = (const float*)d_in[1];
  const float* W_skim = (const float*)d_in[2];
  const float* b_skim = (const float*)d_in[3];
  const float* W_pol  = (const float*)d_in[4];
  const float* b_pol  = (const float*)d_in[5];
  const float* W_eval = (const float*)d_in[6];
  const float* b_eval = (const float*)d_in[7];
  float* out = (float*)d_out;

  char* ws = (char*)d_ws;
  float* partial     = (float*)ws;                         // 768*4096 floats
  int*   idx         = (int*)(ws + (size_t)K1_BLOCKS * 4096 * 4);
  float* pooled_part = (float*)(ws + (size_t)K1_BLOCKS * 4096 * 4 + 1280);

  skim_gemm  <<<K1_BLOCKS, 256, 0, stream>>>(F64, W_skim, partial);
  policy_topk<<<B_SZ, 256, 0, stream>>>(partial, b_skim, W_pol, b_pol, idx);
  gather_pool<<<B_SZ * K_SEL * C_CH * GP_PARTS, 256, 0, stream>>>(F224, idx, pooled_part);
  eval_gemm  <<<B_SZ, 512, 0, stream>>>(pooled_part, W_eval, b_eval, out);
}